// Round 2
// baseline (157.649 us; speedup 1.0000x reference)
//
#include <hip/hip_runtime.h>

#define Bb 32
#define Oo 64
#define FD 512
#define Cc 512
#define Ll 16
#define SQ 256
#define D2 512
#define NN 576  // Cc + Oo
#define QQ 6    // blocks per batch
#define NPB 96  // nodes per block
#define NPW 12  // nodes per wave
#define STAG 17u  // softmax-stats tag (step tags are 1..16)

typedef __attribute__((ext_vector_type(8))) short short8v;
typedef __attribute__((ext_vector_type(4))) float f32x4;
typedef unsigned long long u64;

__device__ inline unsigned short bf16_rne(float f) {
  unsigned u = __builtin_bit_cast(unsigned, f);
  unsigned r = (u + 0x7fffu + ((u >> 16) & 1u)) >> 16;
  return (unsigned short)r;
}
__device__ inline float bf16_to_f(unsigned short h) {
  unsigned u = ((unsigned)h) << 16;
  return __builtin_bit_cast(float, u);
}
__device__ inline u64 pack_tag(float v, unsigned tag) {
  return ((u64)__float_as_uint(v) << 32) | (u64)tag;
}

// ---------------- K1: prep = split_w + zero comm buffers (256 blocks) ----------------
__global__ __launch_bounds__(256) void prep(const float* __restrict__ W,
                                            unsigned short* __restrict__ WH,
                                            unsigned short* __restrict__ WL,
                                            u64* __restrict__ slotG,
                                            u64* __restrict__ slotS) {
  const int gid = blockIdx.x * 256 + threadIdx.x;  // 65536 threads
  // zero slotG (98304 u64) via agent-scope stores
#pragma unroll
  for (int k = 0; k < 2; ++k) {
    const int i = gid * 2 + k;
    if (i < Bb * QQ * 2 * SQ)
      __hip_atomic_store(&slotG[i], 0ULL, __ATOMIC_RELAXED, __HIP_MEMORY_SCOPE_AGENT);
  }
  if (gid < Bb * QQ * 2)
    __hip_atomic_store(&slotS[gid], 0ULL, __ATOMIC_RELAXED, __HIP_MEMORY_SCOPE_AGENT);
  // split W: one float4 group per thread
  const float4 v = ((const float4*)W)[gid];
  float vv[4] = {v.x, v.y, v.z, v.w};
  unsigned short hh[4], ll[4];
#pragma unroll
  for (int j = 0; j < 4; ++j) {
    unsigned short hb = bf16_rne(vv[j]);
    float rem = vv[j] - bf16_to_f(hb);
    hh[j] = hb;
    ll[j] = bf16_rne(rem);
  }
  ushort4 h, lo;
  h.x = hh[0]; h.y = hh[1]; h.z = hh[2]; h.w = hh[3];
  lo.x = ll[0]; lo.y = ll[1]; lo.z = ll[2]; lo.w = ll[3];
  ((ushort4*)WH)[gid] = h;
  ((ushort4*)WL)[gid] = lo;
}

// ---------------- K2: fused bf16x3 MFMA GEMM + node products (+ concept nodes) ----------------
__global__ __launch_bounds__(256) void gemm_nodes(const float* __restrict__ scene,
                                                  const unsigned short* __restrict__ WH,
                                                  const unsigned short* __restrict__ WL,
                                                  const float* __restrict__ bias,
                                                  const float* __restrict__ ct,
                                                  float* __restrict__ cn,
                                                  float* __restrict__ on) {
  __shared__ __align__(16) float sbuf[16 * 529 + 512];
  const int bid = blockIdx.x, tid = threadIdx.x;
  if (bid >= 128) {
    // concept nodes: 8 per block
    float* ls = sbuf;  // 4096 floats
    const int c0 = (bid - 128) * 8;
    for (int i = tid; i < 1024; i += 256)
      ((float4*)ls)[i] = ((const float4*)(ct + (size_t)c0 * D2))[i];
    __syncthreads();
    const int n = tid >> 5, sub = tid & 31;
    const float* n1 = &ls[n * 512];
    const float* n2 = &ls[n * 512 + 256];
    float* dst = cn + (size_t)(c0 + n) * SQ + sub * 8;
#pragma unroll
    for (int j = 0; j < 8; ++j) {
      const int e = sub * 8 + j, i = e >> 4, k = e & 15;
      float s = 0.f;
#pragma unroll
      for (int t = 0; t < 16; ++t) s += n1[i * 16 + t] * n2[t * 16 + k];
      dst[j] = s;
    }
    return;
  }
  float (*objLds)[529] = (float(*)[529])sbuf;
  float* biasL = sbuf + 16 * 529;
  const int wave = tid >> 6, lane = tid & 63;
  const int rowbase = bid * 16;
  for (int i = tid; i < 512; i += 256) biasL[i] = bias[i];

  const int ar = lane & 15;
  const int koff = (lane >> 4) * 8;
  const float* Arow = scene + (size_t)(rowbase + ar) * FD;
  const int ncol0 = wave * 128;
  f32x4 acc[8];
#pragma unroll
  for (int i = 0; i < 8; ++i) acc[i] = (f32x4){0.f, 0.f, 0.f, 0.f};

  for (int k0 = 0; k0 < FD; k0 += 32) {
    float a[8];
    *(float4*)&a[0] = *(const float4*)&Arow[k0 + koff];
    *(float4*)&a[4] = *(const float4*)&Arow[k0 + koff + 4];
    short8v ah, al;
#pragma unroll
    for (int j = 0; j < 8; ++j) {
      unsigned short hb = bf16_rne(a[j]);
      float rem = a[j] - bf16_to_f(hb);
      ah[j] = (short)hb;
      al[j] = (short)bf16_rne(rem);
    }
#pragma unroll
    for (int ni = 0; ni < 8; ++ni) {
      const int d = ncol0 + ni * 16 + ar;
      const short8v wh = *(const short8v*)&WH[(size_t)d * FD + k0 + koff];
      const short8v wl = *(const short8v*)&WL[(size_t)d * FD + k0 + koff];
      acc[ni] = __builtin_amdgcn_mfma_f32_16x16x32_bf16(ah, wh, acc[ni], 0, 0, 0);
      acc[ni] = __builtin_amdgcn_mfma_f32_16x16x32_bf16(ah, wl, acc[ni], 0, 0, 0);
      acc[ni] = __builtin_amdgcn_mfma_f32_16x16x32_bf16(al, wh, acc[ni], 0, 0, 0);
    }
  }
  __syncthreads();
  const int crow = (lane >> 4) * 4;
  const int ccol = lane & 15;
#pragma unroll
  for (int ni = 0; ni < 8; ++ni) {
    const int d = ncol0 + ni * 16 + ccol;
    const float bv = biasL[d];
#pragma unroll
    for (int r = 0; r < 4; ++r) objLds[crow + r][d] = acc[ni][r] + bv;
  }
  __syncthreads();
  const int o = tid >> 4, ii = tid & 15;
  float n1r[16];
#pragma unroll
  for (int j = 0; j < 16; ++j) n1r[j] = objLds[o][ii * 16 + j];
  float* dst = on + (size_t)(rowbase + o) * SQ + ii * 16;
#pragma unroll
  for (int k = 0; k < 16; ++k) {
    float s = 0.f;
#pragma unroll
    for (int j = 0; j < 16; ++j) s += n1r[j] * objLds[o][256 + j * 16 + k];
    dst[k] = s;
  }
}

// ---------------- K3: persistent scan — M-partial exchange, all-wave redundant T/G ----------------
__global__ __launch_bounds__(512) void scan8(const int* __restrict__ ops_p,
                                             const int* __restrict__ pcs,
                                             const float* __restrict__ ct,
                                             const float* __restrict__ cn,
                                             const float* __restrict__ on,
                                             float* __restrict__ out,
                                             u64* __restrict__ slotG,
                                             u64* __restrict__ slotS) {
  const int b = blockIdx.x & 31;
  const int q = blockIdx.x >> 5;
  const int tid = threadIdx.x, wave = tid >> 6, lane = tid & 63;
  __shared__ __align__(16) float ndl[NPB][SQ];    // 96 KB
  __shared__ __align__(16) float Gab[Ll][2 * SQ]; // 32 KB: a1|a2 (verify: G|a2)
  __shared__ __align__(16) float red[8][SQ];      // 8 KB: per-wave M partials
  __shared__ __align__(16) float gbuf[QQ][SQ];    // 6 KB: partner M partials (idx by wave)
  __shared__ float hist[Ll][NPB];                 // 6 KB
  __shared__ __align__(16) float Dls[SQ], Mq[SQ], Tt[SQ];
  __shared__ float attL[NPB];
  __shared__ int opsL[Ll], pcsL[Ll];
  __shared__ float sS[1];

  if (tid < Ll) { opsL[tid] = ops_p[b * Ll + tid]; pcsL[tid] = pcs[b * Ll + tid]; }
  const int n0 = q * NPB;
  for (int idx = tid; idx < NPB * 64; idx += 512) {
    const int r = idx >> 6, c4 = idx & 63;
    const int n = n0 + r;
    const float* src = (n < Cc) ? (cn + (size_t)n * SQ)
                                : (on + ((size_t)b * Oo + (n - Cc)) * SQ);
    *(float4*)&ndl[r][c4 * 4] = *(const float4*)(src + c4 * 4);
  }
  if (tid < SQ) Dls[tid] = cn[tid] - cn[SQ + tid];
  __syncthreads();
  for (int idx = tid; idx < Ll * 128; idx += 512) {
    const int l = idx >> 7, j = idx & 127;
    *(float4*)&Gab[l][j * 4] = *(const float4*)&ct[(size_t)pcsL[l] * D2 + j * 4];
  }
  __syncthreads();
  // ---- prologue: verify-G precompute, wave-parallel (wave w: steps w, w+8) ----
#pragma unroll
  for (int li = 0; li < 2; ++li) {
    const int l = wave + li * 8;
    if (opsL[l] == 0) {
      float t4[4];
#pragma unroll
      for (int j = 0; j < 4; ++j) {  // T = D @ a2^T
        const int e = lane * 4 + j, rr = e >> 4, c = e & 15;
        float s = 0.f;
#pragma unroll
        for (int t = 0; t < 16; ++t) s += Dls[rr * 16 + t] * Gab[l][SQ + c * 16 + t];
        t4[j] = s;
      }
      *(f32x4*)&red[wave][lane * 4] = *(f32x4*)t4;
      asm volatile("s_waitcnt lgkmcnt(0)" ::: "memory");
      __builtin_amdgcn_sched_barrier(0);
      float g4[4];
#pragma unroll
      for (int j = 0; j < 4; ++j) {  // G = a1 @ T
        const int e = lane * 4 + j, rr = e >> 4, c = e & 15;
        float s = 0.f;
#pragma unroll
        for (int t = 0; t < 16; ++t) s += Gab[l][rr * 16 + t] * red[wave][t * 16 + c];
        g4[j] = s;
      }
      *(f32x4*)&Gab[l][lane * 4] = *(f32x4*)g4;
    }
  }
  // initial per-wave m (att = 1)
  f32x4 m = (f32x4){0.f, 0.f, 0.f, 0.f};
#pragma unroll
  for (int ni = 0; ni < NPW; ++ni)
    m += *(const f32x4*)&ndl[wave * NPW + ni][lane * 4];
  __syncthreads();  // Gab/red prologue writes visible

  float att[NPW];
#pragma unroll
  for (int ni = 0; ni < NPW; ++ni) att[ni] = 1.f;

  const int r16 = lane >> 2, c0 = (lane & 3) * 4;  // element lane*4+j == (r16, c0+j)
  int tc = 0;  // transfer-step count (uniform across the batch's blocks)
  for (int l = 0; l < Ll; ++l) {
    const bool verify = (opsL[l] == 0);
    if (!verify) {
      const int par = tc & 1;
      ++tc;
      const unsigned tg = (unsigned)(l + 1);
      *(f32x4*)&red[wave][lane * 4] = m;
      __syncthreads();  // B1: all per-wave partials in red
      // all waves: in-block reduce (identical values across waves)
      f32x4 s = (f32x4){0.f, 0.f, 0.f, 0.f};
#pragma unroll
      for (int w = 0; w < 8; ++w) s += *(const f32x4*)&red[w][lane * 4];
      if (wave == 0) {
        // ---- post block M-partial, tagged (fire-and-forget) ----
        u64* myslot = slotG + ((size_t)(b * QQ + q) * 2 + par) * SQ;
#pragma unroll
        for (int j = 0; j < 4; ++j)
          __hip_atomic_store(&myslot[lane * 4 + j], pack_tag(s[j], tg),
                             __ATOMIC_RELAXED, __HIP_MEMORY_SCOPE_AGENT);
      } else if (wave <= QQ - 1) {
        // ---- consumer: sentinel poll, then validated bulk read ----
        const int qq = (q + wave) % QQ;
        const u64* base = slotG + ((size_t)(b * QQ + qq) * 2 + par) * SQ;
        if (lane == 0) {
          while ((unsigned)__hip_atomic_load(base + (SQ - 1), __ATOMIC_RELAXED,
                                             __HIP_MEMORY_SCOPE_AGENT) != tg) {}
        }
        u64 pk[4];
        for (;;) {
#pragma unroll
          for (int j = 0; j < 4; ++j)
            pk[j] = __hip_atomic_load(base + lane * 4 + j, __ATOMIC_RELAXED,
                                      __HIP_MEMORY_SCOPE_AGENT);
          bool ok = true;
#pragma unroll
          for (int j = 0; j < 4; ++j) ok &= ((unsigned)pk[j] == tg);
          if (__all(ok)) break;
        }
#pragma unroll
        for (int j = 0; j < 4; ++j)
          gbuf[wave][lane * 4 + j] = __uint_as_float((unsigned)(pk[j] >> 32));
      }
      __syncthreads();  // B2: partner partials in gbuf
      // ---- every wave: M = own + 5 partners (identical across waves) ----
      f32x4 M4 = s;
#pragma unroll
      for (int w = 1; w < QQ; ++w) M4 += *(const f32x4*)&gbuf[w][lane * 4];
      *(f32x4*)&Mq[lane * 4] = M4;  // benign identical-value race across waves
      asm volatile("s_waitcnt lgkmcnt(0)" ::: "memory");
      __builtin_amdgcn_sched_barrier(0);
      // ---- T = a1^T @ M (vectorized) ----
      f32x4 T4 = (f32x4){0.f, 0.f, 0.f, 0.f};
#pragma unroll
      for (int t = 0; t < 16; ++t) {
        const float a1v = Gab[l][t * 16 + r16];
        const f32x4 mv = *(const f32x4*)&Mq[t * 16 + c0];
        T4[0] += a1v * mv[0]; T4[1] += a1v * mv[1];
        T4[2] += a1v * mv[2]; T4[3] += a1v * mv[3];
      }
      *(f32x4*)&Tt[lane * 4] = T4;  // benign identical-value race across waves
      asm volatile("s_waitcnt lgkmcnt(0)" ::: "memory");
      __builtin_amdgcn_sched_barrier(0);
      // preload own T row (avoids scalar bank-conflicted reads in G stage)
      f32x4 tr[4];
#pragma unroll
      for (int k = 0; k < 4; ++k) tr[k] = *(const f32x4*)&Tt[r16 * 16 + k * 4];
      // ---- G = T @ a2 (per-lane result == exactly the G slice this lane needs) ----
      f32x4 gg = (f32x4){0.f, 0.f, 0.f, 0.f};
#pragma unroll
      for (int t = 0; t < 16; ++t) {
        const float trv = tr[t >> 2][t & 3];
        const f32x4 a2v = *(const f32x4*)&Gab[l][SQ + t * 16 + c0];
        gg[0] += trv * a2v[0]; gg[1] += trv * a2v[1];
        gg[2] += trv * a2v[2]; gg[3] += trv * a2v[3];
      }
      // ---- node pass (transfer) ----
      f32x4 mn = (f32x4){0.f, 0.f, 0.f, 0.f};
#pragma unroll
      for (int ni = 0; ni < NPW; ++ni) {
        const int nl = wave * NPW + ni;
        const f32x4 v = *(const f32x4*)&ndl[nl][lane * 4];
        float p = v[0] * gg[0] + v[1] * gg[1] + v[2] * gg[2] + v[3] * gg[3];
        p += __shfl_xor(p, 1);  p += __shfl_xor(p, 2);  p += __shfl_xor(p, 4);
        p += __shfl_xor(p, 8);  p += __shfl_xor(p, 16); p += __shfl_xor(p, 32);
        const float na = fminf(fmaxf(p, -1.f), 5.f) + 0.1f * p;
        att[ni] = na;
        if (lane == 0) hist[l][nl] = na;
        mn[0] += na * v[0]; mn[1] += na * v[1]; mn[2] += na * v[2]; mn[3] += na * v[3];
      }
      m = mn;
    } else {
      // ---- verify: fully wave-local ----
      const f32x4 g = *(const f32x4*)&Gab[l][lane * 4];
      f32x4 mn = (f32x4){0.f, 0.f, 0.f, 0.f};
#pragma unroll
      for (int ni = 0; ni < NPW; ++ni) {
        const int nl = wave * NPW + ni;
        const f32x4 v = *(const f32x4*)&ndl[nl][lane * 4];
        float p = v[0] * g[0] + v[1] * g[1] + v[2] * g[2] + v[3] * g[3];
        p += __shfl_xor(p, 1);  p += __shfl_xor(p, 2);  p += __shfl_xor(p, 4);
        p += __shfl_xor(p, 8);  p += __shfl_xor(p, 16); p += __shfl_xor(p, 32);
        const float x = att[ni] * p;
        const float na = fminf(fmaxf(x, -1.f), 5.f) + 0.1f * x;
        att[ni] = na;
        if (lane == 0) hist[l][nl] = na;
        mn[0] += na * v[0]; mn[1] += na * v[1]; mn[2] += na * v[2]; mn[3] += na * v[3];
      }
      m = mn;
    }
  }
  if (lane == 0) {
#pragma unroll
    for (int ni = 0; ni < NPW; ++ni) attL[wave * NPW + ni] = att[ni];
  }
  __syncthreads();  // attL / hist complete

  // ---- final log_softmax across the 6 blocks (wave0, tagged exchange) ----
  if (wave == 0) {
    float mv = -1e30f;
    for (int i = lane; i < NPB; i += 64) mv = fmaxf(mv, attL[i]);
    mv = fmaxf(mv, __shfl_xor(mv, 1));  mv = fmaxf(mv, __shfl_xor(mv, 2));
    mv = fmaxf(mv, __shfl_xor(mv, 4));  mv = fmaxf(mv, __shfl_xor(mv, 8));
    mv = fmaxf(mv, __shfl_xor(mv, 16)); mv = fmaxf(mv, __shfl_xor(mv, 32));
    float sv = 0.f;
    for (int i = lane; i < NPB; i += 64) sv += expf(attL[i] - mv);
    sv += __shfl_xor(sv, 1);  sv += __shfl_xor(sv, 2);  sv += __shfl_xor(sv, 4);
    sv += __shfl_xor(sv, 8);  sv += __shfl_xor(sv, 16); sv += __shfl_xor(sv, 32);
    if (lane == 0) {
      __hip_atomic_store(&slotS[(b * QQ + q) * 2 + 0], pack_tag(mv, STAG),
                         __ATOMIC_RELAXED, __HIP_MEMORY_SCOPE_AGENT);
      __hip_atomic_store(&slotS[(b * QQ + q) * 2 + 1], pack_tag(sv, STAG),
                         __ATOMIC_RELAXED, __HIP_MEMORY_SCOPE_AGENT);
    }
    const int role = (lane < QQ) ? 0 : ((lane >= 8 && lane < 8 + QQ) ? 1 : -1);
    const int sidx = (role == 0) ? ((b * QQ + lane) * 2)
                                 : ((role == 1) ? ((b * QQ + (lane - 8)) * 2 + 1) : 0);
    u64 pk;
    for (;;) {
      pk = (role >= 0) ? __hip_atomic_load(&slotS[sidx], __ATOMIC_RELAXED,
                                           __HIP_MEMORY_SCOPE_AGENT)
                       : (u64)STAG;
      if (__all((unsigned)pk == STAG)) break;
    }
    const float v = __uint_as_float((unsigned)(pk >> 32));
    float gM = -1e30f, gT = 0.f;
#pragma unroll
    for (int qq = 0; qq < QQ; ++qq) gM = fmaxf(gM, __shfl(v, qq));
#pragma unroll
    for (int qq = 0; qq < QQ; ++qq)
      gT += __shfl(v, 8 + qq) * expf(__shfl(v, qq) - gM);
    if (lane == 0) sS[0] = gM + logf(gT);
  }
  __syncthreads();
  const float lse = sS[0];
  if (tid < NPB) out[(size_t)b * NN + n0 + tid] = attL[tid] - lse;
  for (int idx = tid; idx < Ll * NPB; idx += 512) {
    const int l = idx / NPB, i = idx - l * NPB;
    out[(size_t)Bb * NN + ((size_t)l * Bb + b) * NN + n0 + i] = hist[l][i];
  }
}

extern "C" void kernel_launch(void* const* d_in, const int* in_sizes, int n_in,
                              void* d_out, int out_size, void* d_ws, size_t ws_size,
                              hipStream_t stream) {
  const float* scene = (const float*)d_in[0];
  const int* ops = (const int*)d_in[1];
  const int* pcs = (const int*)d_in[2];
  const float* ct = (const float*)d_in[3];
  const float* fW = (const float*)d_in[4];
  const float* fb = (const float*)d_in[5];
  float* out = (float*)d_out;
  float* ws = (float*)d_ws;

  float* cn = ws;                                      // 131072 f
  float* on = cn + (size_t)Cc * SQ;                    // 524288 f
  unsigned short* WH = (unsigned short*)(on + (size_t)Bb * Oo * SQ);  // 512 KB
  unsigned short* WL = WH + (size_t)D2 * FD;                          // 512 KB
  u64* slotG = (u64*)(WL + (size_t)D2 * FD);           // 98304 u64 = 768 KB
  u64* slotS = slotG + (size_t)Bb * QQ * 2 * SQ;       // 384 u64

  prep<<<256, 256, 0, stream>>>(fW, WH, WL, slotG, slotS);
  gemm_nodes<<<192, 256, 0, stream>>>(scene, WH, WL, fb, ct, cn, on);
  scan8<<<Bb * QQ, 512, 0, stream>>>(ops, pcs, ct, cn, on, out, slotG, slotS);
}

// Round 3
// 140.726 us; speedup vs baseline: 1.1203x; 1.1203x over previous
//
#include <hip/hip_runtime.h>

#define Bb 32
#define Oo 64
#define FD 512
#define Cc 512
#define Ll 16
#define SQ 256
#define D2 512
#define NN 576  // Cc + Oo
#define QQ 6    // blocks per batch
#define NPB 96  // nodes per block
#define NPW 12  // nodes per wave
#define STAG 17u  // softmax-stats tag (step tags are 1..16)

typedef __attribute__((ext_vector_type(8))) short short8v;
typedef __attribute__((ext_vector_type(4))) float f32x4;
typedef unsigned long long u64;

__device__ inline unsigned short bf16_rne(float f) {
  unsigned u = __builtin_bit_cast(unsigned, f);
  unsigned r = (u + 0x7fffu + ((u >> 16) & 1u)) >> 16;
  return (unsigned short)r;
}
__device__ inline float bf16_to_f(unsigned short h) {
  unsigned u = ((unsigned)h) << 16;
  return __builtin_bit_cast(float, u);
}
__device__ inline u64 pack_tag(float v, unsigned tag) {
  return ((u64)__float_as_uint(v) << 32) | (u64)tag;
}

// ---------------- K1: prep = split_w + zero comm buffers (256 blocks) ----------------
__global__ __launch_bounds__(256) void prep(const float* __restrict__ W,
                                            unsigned short* __restrict__ WH,
                                            unsigned short* __restrict__ WL,
                                            u64* __restrict__ slotG,
                                            u64* __restrict__ slotS) {
  const int gid = blockIdx.x * 256 + threadIdx.x;  // 65536 threads
  // zero slotG (98304 u64) via agent-scope stores
#pragma unroll
  for (int k = 0; k < 2; ++k) {
    const int i = gid * 2 + k;
    if (i < Bb * QQ * 2 * SQ)
      __hip_atomic_store(&slotG[i], 0ULL, __ATOMIC_RELAXED, __HIP_MEMORY_SCOPE_AGENT);
  }
  if (gid < Bb * QQ * 2)
    __hip_atomic_store(&slotS[gid], 0ULL, __ATOMIC_RELAXED, __HIP_MEMORY_SCOPE_AGENT);
  // split W: one float4 group per thread
  const float4 v = ((const float4*)W)[gid];
  float vv[4] = {v.x, v.y, v.z, v.w};
  unsigned short hh[4], ll[4];
#pragma unroll
  for (int j = 0; j < 4; ++j) {
    unsigned short hb = bf16_rne(vv[j]);
    float rem = vv[j] - bf16_to_f(hb);
    hh[j] = hb;
    ll[j] = bf16_rne(rem);
  }
  ushort4 h, lo;
  h.x = hh[0]; h.y = hh[1]; h.z = hh[2]; h.w = hh[3];
  lo.x = ll[0]; lo.y = ll[1]; lo.z = ll[2]; lo.w = ll[3];
  ((ushort4*)WH)[gid] = h;
  ((ushort4*)WL)[gid] = lo;
}

// ---------------- K2: fused bf16x3 MFMA GEMM + node products (+ concept nodes) ----------------
__global__ __launch_bounds__(256) void gemm_nodes(const float* __restrict__ scene,
                                                  const unsigned short* __restrict__ WH,
                                                  const unsigned short* __restrict__ WL,
                                                  const float* __restrict__ bias,
                                                  const float* __restrict__ ct,
                                                  float* __restrict__ cn,
                                                  float* __restrict__ on) {
  __shared__ __align__(16) float sbuf[16 * 529 + 512];
  const int bid = blockIdx.x, tid = threadIdx.x;
  if (bid >= 128) {
    // concept nodes: 8 per block
    float* ls = sbuf;  // 4096 floats
    const int c0 = (bid - 128) * 8;
    for (int i = tid; i < 1024; i += 256)
      ((float4*)ls)[i] = ((const float4*)(ct + (size_t)c0 * D2))[i];
    __syncthreads();
    const int n = tid >> 5, sub = tid & 31;
    const float* n1 = &ls[n * 512];
    const float* n2 = &ls[n * 512 + 256];
    float* dst = cn + (size_t)(c0 + n) * SQ + sub * 8;
#pragma unroll
    for (int j = 0; j < 8; ++j) {
      const int e = sub * 8 + j, i = e >> 4, k = e & 15;
      float s = 0.f;
#pragma unroll
      for (int t = 0; t < 16; ++t) s += n1[i * 16 + t] * n2[t * 16 + k];
      dst[j] = s;
    }
    return;
  }
  float (*objLds)[529] = (float(*)[529])sbuf;
  float* biasL = sbuf + 16 * 529;
  const int wave = tid >> 6, lane = tid & 63;
  const int rowbase = bid * 16;
  for (int i = tid; i < 512; i += 256) biasL[i] = bias[i];

  const int ar = lane & 15;
  const int koff = (lane >> 4) * 8;
  const float* Arow = scene + (size_t)(rowbase + ar) * FD;
  const int ncol0 = wave * 128;
  f32x4 acc[8];
#pragma unroll
  for (int i = 0; i < 8; ++i) acc[i] = (f32x4){0.f, 0.f, 0.f, 0.f};

  for (int k0 = 0; k0 < FD; k0 += 32) {
    float a[8];
    *(float4*)&a[0] = *(const float4*)&Arow[k0 + koff];
    *(float4*)&a[4] = *(const float4*)&Arow[k0 + koff + 4];
    short8v ah, al;
#pragma unroll
    for (int j = 0; j < 8; ++j) {
      unsigned short hb = bf16_rne(a[j]);
      float rem = a[j] - bf16_to_f(hb);
      ah[j] = (short)hb;
      al[j] = (short)bf16_rne(rem);
    }
#pragma unroll
    for (int ni = 0; ni < 8; ++ni) {
      const int d = ncol0 + ni * 16 + ar;
      const short8v wh = *(const short8v*)&WH[(size_t)d * FD + k0 + koff];
      const short8v wl = *(const short8v*)&WL[(size_t)d * FD + k0 + koff];
      acc[ni] = __builtin_amdgcn_mfma_f32_16x16x32_bf16(ah, wh, acc[ni], 0, 0, 0);
      acc[ni] = __builtin_amdgcn_mfma_f32_16x16x32_bf16(ah, wl, acc[ni], 0, 0, 0);
      acc[ni] = __builtin_amdgcn_mfma_f32_16x16x32_bf16(al, wh, acc[ni], 0, 0, 0);
    }
  }
  __syncthreads();
  const int crow = (lane >> 4) * 4;
  const int ccol = lane & 15;
#pragma unroll
  for (int ni = 0; ni < 8; ++ni) {
    const int d = ncol0 + ni * 16 + ccol;
    const float bv = biasL[d];
#pragma unroll
    for (int r = 0; r < 4; ++r) objLds[crow + r][d] = acc[ni][r] + bv;
  }
  __syncthreads();
  const int o = tid >> 4, ii = tid & 15;
  float n1r[16];
#pragma unroll
  for (int j = 0; j < 16; ++j) n1r[j] = objLds[o][ii * 16 + j];
  float* dst = on + (size_t)(rowbase + o) * SQ + ii * 16;
#pragma unroll
  for (int k = 0; k < 16; ++k) {
    float s = 0.f;
#pragma unroll
    for (int j = 0; j < 16; ++j) s += n1r[j] * objLds[o][256 + j * 16 + k];
    dst[k] = s;
  }
}

// ---------------- K3: persistent scan, G-exchange + sentinel poll (R0 protocol,
// wave0 T/G chain vectorized; posted store pattern byte-identical to R0) ----------------
__global__ __launch_bounds__(512) void scan8(const int* __restrict__ ops_p,
                                             const int* __restrict__ pcs,
                                             const float* __restrict__ ct,
                                             const float* __restrict__ cn,
                                             const float* __restrict__ on,
                                             float* __restrict__ out,
                                             u64* __restrict__ slotG,
                                             u64* __restrict__ slotS) {
  const int b = blockIdx.x & 31;
  const int q = blockIdx.x >> 5;
  const int tid = threadIdx.x, wave = tid >> 6, lane = tid & 63;
  __shared__ __align__(16) float ndl[NPB][SQ];    // 96 KB
  __shared__ __align__(16) float Gab[Ll][2 * SQ]; // 32 KB: a1|a2 (verify: G|a2)
  __shared__ __align__(16) float red[8][SQ];      // 8 KB
  __shared__ __align__(16) float gbuf[QQ][SQ];    // 6 KB
  __shared__ float hist[Ll][NPB];                 // 6 KB
  __shared__ __align__(16) float Dls[SQ], Mq[SQ], Tt[SQ];
  __shared__ float attL[NPB];
  __shared__ int opsL[Ll], pcsL[Ll];
  __shared__ float sS[1];

  if (tid < Ll) { opsL[tid] = ops_p[b * Ll + tid]; pcsL[tid] = pcs[b * Ll + tid]; }
  const int n0 = q * NPB;
  for (int idx = tid; idx < NPB * 64; idx += 512) {
    const int r = idx >> 6, c4 = idx & 63;
    const int n = n0 + r;
    const float* src = (n < Cc) ? (cn + (size_t)n * SQ)
                                : (on + ((size_t)b * Oo + (n - Cc)) * SQ);
    *(float4*)&ndl[r][c4 * 4] = *(const float4*)(src + c4 * 4);
  }
  if (tid < SQ) Dls[tid] = cn[tid] - cn[SQ + tid];
  if (tid < NPB) attL[tid] = 1.f;
  __syncthreads();
  for (int idx = tid; idx < Ll * 128; idx += 512) {
    const int l = idx >> 7, j = idx & 127;
    *(float4*)&Gab[l][j * 4] = *(const float4*)&ct[(size_t)pcsL[l] * D2 + j * 4];
  }
  __syncthreads();
  // ---- prologue: verify-G precompute, wave-parallel (wave w: steps w, w+8) ----
#pragma unroll
  for (int li = 0; li < 2; ++li) {
    const int l = wave + li * 8;
    if (opsL[l] == 0) {
      float t4[4];
#pragma unroll
      for (int j = 0; j < 4; ++j) {  // T = D @ a2^T
        const int e = lane * 4 + j, r = e >> 4, c = e & 15;
        float s = 0.f;
#pragma unroll
        for (int t = 0; t < 16; ++t) s += Dls[r * 16 + t] * Gab[l][SQ + c * 16 + t];
        t4[j] = s;
      }
      *(f32x4*)&red[wave][lane * 4] = *(f32x4*)t4;
      asm volatile("s_waitcnt lgkmcnt(0)" ::: "memory");
      __builtin_amdgcn_sched_barrier(0);
      float g4[4];
#pragma unroll
      for (int j = 0; j < 4; ++j) {  // G = a1 @ T
        const int e = lane * 4 + j, r = e >> 4, c = e & 15;
        float s = 0.f;
#pragma unroll
        for (int t = 0; t < 16; ++t) s += Gab[l][r * 16 + t] * red[wave][t * 16 + c];
        g4[j] = s;
      }
      *(f32x4*)&Gab[l][lane * 4] = *(f32x4*)g4;
    }
  }
  // initial per-wave m (att = 1)
  f32x4 m = (f32x4){0.f, 0.f, 0.f, 0.f};
#pragma unroll
  for (int ni = 0; ni < NPW; ++ni)
    m += *(const f32x4*)&ndl[wave * NPW + ni][lane * 4];
  __syncthreads();  // Gab prologue writes visible

  const int r16 = lane >> 2, c0 = (lane & 3) * 4;  // element lane*4+j == (r16, c0+j)
  int tc = 0;  // transfer-step count (uniform across the batch's blocks)
  for (int l = 0; l < Ll; ++l) {
    const bool verify = (opsL[l] == 0);
    if (!verify) {
      const int par = tc & 1;
      ++tc;
      const unsigned tg = (unsigned)(l + 1);
      *(f32x4*)&red[wave][lane * 4] = m;
      __syncthreads();  // B1
      if (wave == 0) {
        // ---- post tail: reduce -> T -> G_q -> LLC (vectorized, fire-and-forget) ----
        f32x4 s = (f32x4){0.f, 0.f, 0.f, 0.f};
#pragma unroll
        for (int w = 0; w < 8; ++w) s += *(const f32x4*)&red[w][lane * 4];
        *(f32x4*)&Mq[lane * 4] = s;
        asm volatile("s_waitcnt lgkmcnt(0)" ::: "memory");
        __builtin_amdgcn_sched_barrier(0);
        // T = a1^T @ M (vectorized: broadcast a1 col + b128 M rows)
        f32x4 T4 = (f32x4){0.f, 0.f, 0.f, 0.f};
#pragma unroll
        for (int t = 0; t < 16; ++t) {
          const float a1v = Gab[l][t * 16 + r16];
          const f32x4 mv = *(const f32x4*)&Mq[t * 16 + c0];
          T4[0] += a1v * mv[0]; T4[1] += a1v * mv[1];
          T4[2] += a1v * mv[2]; T4[3] += a1v * mv[3];
        }
        *(f32x4*)&Tt[lane * 4] = T4;  // Tt row-major: element lane*4+j == T[r16][c0+j]
        asm volatile("s_waitcnt lgkmcnt(0)" ::: "memory");
        __builtin_amdgcn_sched_barrier(0);
        // preload own T row as b128 (avoids bank-conflicted scalar reads)
        f32x4 tr[4];
#pragma unroll
        for (int k = 0; k < 4; ++k) tr[k] = *(const f32x4*)&Tt[r16 * 16 + k * 4];
        // G = T @ a2 ; result g[j] = G[lane*4+j]
        f32x4 g = (f32x4){0.f, 0.f, 0.f, 0.f};
#pragma unroll
        for (int t = 0; t < 16; ++t) {
          const float trv = tr[t >> 2][t & 3];
          const f32x4 a2v = *(const f32x4*)&Gab[l][SQ + t * 16 + c0];
          g[0] += trv * a2v[0]; g[1] += trv * a2v[1];
          g[2] += trv * a2v[2]; g[3] += trv * a2v[3];
        }
        // stage into gbuf[q] (needed there anyway), then post in R0's j*64+lane order
        *(f32x4*)&gbuf[q][lane * 4] = g;
        asm volatile("s_waitcnt lgkmcnt(0)" ::: "memory");
        __builtin_amdgcn_sched_barrier(0);
        u64* myslot = slotG + ((size_t)(b * QQ + q) * 2 + par) * SQ;
#pragma unroll
        for (int j = 0; j < 4; ++j) {
          const float gv = gbuf[q][j * 64 + lane];
          __hip_atomic_store(&myslot[j * 64 + lane], pack_tag(gv, tg),
                             __ATOMIC_RELAXED, __HIP_MEMORY_SCOPE_AGENT);
        }
      } else if (wave <= QQ - 1) {
        // ---- consumer: sentinel poll, then validated bulk read (R0 pattern) ----
        const int qq = (q + wave) % QQ;
        const u64* base = slotG + ((size_t)(b * QQ + qq) * 2 + par) * SQ;
        if (lane == 0) {
          while ((unsigned)__hip_atomic_load(base + (SQ - 1), __ATOMIC_RELAXED,
                                             __HIP_MEMORY_SCOPE_AGENT) != tg) {}
        }
        u64 pk[4];
        for (;;) {
#pragma unroll
          for (int j = 0; j < 4; ++j)
            pk[j] = __hip_atomic_load(base + j * 64 + lane, __ATOMIC_RELAXED,
                                      __HIP_MEMORY_SCOPE_AGENT);
          bool ok = true;
#pragma unroll
          for (int j = 0; j < 4; ++j) ok &= ((unsigned)pk[j] == tg);
          if (__all(ok)) break;
        }
#pragma unroll
        for (int j = 0; j < 4; ++j)
          gbuf[qq][j * 64 + lane] = __uint_as_float((unsigned)(pk[j] >> 32));
      }
      __syncthreads();  // B2: gbuf complete
      // G = sum of 6 partials, read per-wave from LDS
      f32x4 gg = (f32x4){0.f, 0.f, 0.f, 0.f};
#pragma unroll
      for (int qq = 0; qq < QQ; ++qq) gg += *(const f32x4*)&gbuf[qq][lane * 4];
      // ---- node pass (transfer) ----
      f32x4 mn = (f32x4){0.f, 0.f, 0.f, 0.f};
#pragma unroll
      for (int ni = 0; ni < NPW; ++ni) {
        const int nl = wave * NPW + ni;
        const f32x4 v = *(const f32x4*)&ndl[nl][lane * 4];
        float p = v[0] * gg[0] + v[1] * gg[1] + v[2] * gg[2] + v[3] * gg[3];
        p += __shfl_xor(p, 1);  p += __shfl_xor(p, 2);  p += __shfl_xor(p, 4);
        p += __shfl_xor(p, 8);  p += __shfl_xor(p, 16); p += __shfl_xor(p, 32);
        const float na = fminf(fmaxf(p, -1.f), 5.f) + 0.1f * p;
        if (lane == 0) { attL[nl] = na; hist[l][nl] = na; }
        mn[0] += na * v[0]; mn[1] += na * v[1]; mn[2] += na * v[2]; mn[3] += na * v[3];
      }
      m = mn;
    } else {
      const f32x4 g = *(const f32x4*)&Gab[l][lane * 4];
      f32x4 mn = (f32x4){0.f, 0.f, 0.f, 0.f};
#pragma unroll
      for (int ni = 0; ni < NPW; ++ni) {
        const int nl = wave * NPW + ni;
        const f32x4 v = *(const f32x4*)&ndl[nl][lane * 4];
        float p = v[0] * g[0] + v[1] * g[1] + v[2] * g[2] + v[3] * g[3];
        p += __shfl_xor(p, 1);  p += __shfl_xor(p, 2);  p += __shfl_xor(p, 4);
        p += __shfl_xor(p, 8);  p += __shfl_xor(p, 16); p += __shfl_xor(p, 32);
        const float x = attL[nl] * p;
        const float na = fminf(fmaxf(x, -1.f), 5.f) + 0.1f * x;
        if (lane == 0) { attL[nl] = na; hist[l][nl] = na; }
        mn[0] += na * v[0]; mn[1] += na * v[1]; mn[2] += na * v[2]; mn[3] += na * v[3];
      }
      m = mn;
    }
  }
  __syncthreads();  // attL / hist complete

  // ---- final log_softmax across the 6 blocks (wave0, tagged exchange) ----
  if (wave == 0) {
    float mv = -1e30f;
    for (int i = lane; i < NPB; i += 64) mv = fmaxf(mv, attL[i]);
    mv = fmaxf(mv, __shfl_xor(mv, 1));  mv = fmaxf(mv, __shfl_xor(mv, 2));
    mv = fmaxf(mv, __shfl_xor(mv, 4));  mv = fmaxf(mv, __shfl_xor(mv, 8));
    mv = fmaxf(mv, __shfl_xor(mv, 16)); mv = fmaxf(mv, __shfl_xor(mv, 32));
    float sv = 0.f;
    for (int i = lane; i < NPB; i += 64) sv += expf(attL[i] - mv);
    sv += __shfl_xor(sv, 1);  sv += __shfl_xor(sv, 2);  sv += __shfl_xor(sv, 4);
    sv += __shfl_xor(sv, 8);  sv += __shfl_xor(sv, 16); sv += __shfl_xor(sv, 32);
    if (lane == 0) {
      __hip_atomic_store(&slotS[(b * QQ + q) * 2 + 0], pack_tag(mv, STAG),
                         __ATOMIC_RELAXED, __HIP_MEMORY_SCOPE_AGENT);
      __hip_atomic_store(&slotS[(b * QQ + q) * 2 + 1], pack_tag(sv, STAG),
                         __ATOMIC_RELAXED, __HIP_MEMORY_SCOPE_AGENT);
    }
    const int role = (lane < QQ) ? 0 : ((lane >= 8 && lane < 8 + QQ) ? 1 : -1);
    const int sidx = (role == 0) ? ((b * QQ + lane) * 2)
                                 : ((role == 1) ? ((b * QQ + (lane - 8)) * 2 + 1) : 0);
    u64 pk;
    for (;;) {
      pk = (role >= 0) ? __hip_atomic_load(&slotS[sidx], __ATOMIC_RELAXED,
                                           __HIP_MEMORY_SCOPE_AGENT)
                       : (u64)STAG;
      if (__all((unsigned)pk == STAG)) break;
    }
    const float v = __uint_as_float((unsigned)(pk >> 32));
    float gM = -1e30f, gT = 0.f;
#pragma unroll
    for (int qq = 0; qq < QQ; ++qq) gM = fmaxf(gM, __shfl(v, qq));
#pragma unroll
    for (int qq = 0; qq < QQ; ++qq)
      gT += __shfl(v, 8 + qq) * expf(__shfl(v, qq) - gM);
    if (lane == 0) sS[0] = gM + logf(gT);
  }
  __syncthreads();
  const float lse = sS[0];
  if (tid < NPB) out[(size_t)b * NN + n0 + tid] = attL[tid] - lse;
  for (int idx = tid; idx < Ll * NPB; idx += 512) {
    const int l = idx / NPB, i = idx - l * NPB;
    out[(size_t)Bb * NN + ((size_t)l * Bb + b) * NN + n0 + i] = hist[l][i];
  }
}

extern "C" void kernel_launch(void* const* d_in, const int* in_sizes, int n_in,
                              void* d_out, int out_size, void* d_ws, size_t ws_size,
                              hipStream_t stream) {
  const float* scene = (const float*)d_in[0];
  const int* ops = (const int*)d_in[1];
  const int* pcs = (const int*)d_in[2];
  const float* ct = (const float*)d_in[3];
  const float* fW = (const float*)d_in[4];
  const float* fb = (const float*)d_in[5];
  float* out = (float*)d_out;
  float* ws = (float*)d_ws;

  float* cn = ws;                                      // 131072 f
  float* on = cn + (size_t)Cc * SQ;                    // 524288 f
  unsigned short* WH = (unsigned short*)(on + (size_t)Bb * Oo * SQ);  // 512 KB
  unsigned short* WL = WH + (size_t)D2 * FD;                          // 512 KB
  u64* slotG = (u64*)(WL + (size_t)D2 * FD);           // 98304 u64 = 768 KB
  u64* slotS = slotG + (size_t)Bb * QQ * 2 * SQ;       // 384 u64

  prep<<<256, 256, 0, stream>>>(fW, WH, WL, slotG, slotS);
  gemm_nodes<<<192, 256, 0, stream>>>(scene, WH, WL, fb, ct, cn, on);
  scan8<<<Bb * QQ, 512, 0, stream>>>(ops, pcs, ct, cn, on, out, slotG, slotS);
}